// Round 13
// baseline (216.218 us; speedup 1.0000x reference)
//
#include <hip/hip_runtime.h>
#include <hip/hip_bf16.h>
#include <hip/hip_cooperative_groups.h>

namespace cg = cooperative_groups;

// Problem constants
#define B 256
#define S 256
#define H 768
#define C 150
#define H4 192              // H / 4 (float4 columns)

// ws layout (bytes):
//  prelogits : 0        .. 786432    [256][768] f32
//  dp        : 786432   .. 2015232   [8][256][150] f32 score-dot partials
//  tx_part   : 2015232  .. 2023424   [8][256] f32
//  tm_part   : 2023424  .. 2028288   [8][152] f32

// ---------------------------------------------------------------------------
// kMega (cooperative): 256 blocks x 768 threads, 1 block/CU.
//  phase 1: masked pool, block b -> prelogits[b]           (HBM-bound)
//  phase 2: xS GEMM tile (rt,cs) -> tx_part + dp; blocks 0..151 then tm job
//  phase 3: per-b score reduce + argmin -> out
// ---------------------------------------------------------------------------
__global__ __launch_bounds__(768) void kMega(const float* __restrict__ lhs,
                                             const int* __restrict__ mask,
                                             const float* __restrict__ means,
                                             const float* __restrict__ cov,
                                             float* __restrict__ prelogits,
                                             float* __restrict__ dp,
                                             float* __restrict__ tx_part,
                                             float* __restrict__ tm_part,
                                             float* __restrict__ out) {
    cg::grid_group grid = cg::this_grid();
    const int bid = blockIdx.x;
    const int t = threadIdx.x;

    __shared__ float msk[S];              // 1 KB   (phase 1)
    __shared__ float4 qbuf[3][H4];        // 9 KB   (phase 1)
    __shared__ float cntsh;
    __shared__ float xsl[8 * H];          // 24 KB  (phases 2a/2b)
    __shared__ float4 red2[32][24];       // 12 KB  (phase 2a)
    __shared__ float4 xsf[8][24];         // 3 KB   (phase 2a)
    __shared__ float sred[8][12];         // 384 B  (phase 2b)
    __shared__ float sv[192];             // phase 3
    __shared__ int si[192];

    // ================= phase 1: pool (b = bid) =================
    {
        const int b = bid;
        const int q = t / H4, c4 = t - q * H4;   // quarter 0..3, f4-col
        if (t < S) msk[t] = (float)mask[b * S + t];
        __syncthreads();
        if (t >= 704) {
            const int idx = t - 704;
            float v = msk[idx] + msk[idx + 64] + msk[idx + 128] + msk[idx + 192];
#pragma unroll
            for (int off = 32; off > 0; off >>= 1) v += __shfl_down(v, off, 64);
            if (idx == 0) cntsh = v;
        }
        const float4* src = (const float4*)lhs + (size_t)(b * S + q * 64) * H4 + c4;
        const float* mrow = msk + q * 64;
        float4 acc = make_float4(0.f, 0.f, 0.f, 0.f);
#pragma unroll 8
        for (int s = 0; s < 64; ++s) {
            const float m = mrow[s];
            const float4 v = src[(size_t)s * H4];
            acc.x += v.x * m; acc.y += v.y * m; acc.z += v.z * m; acc.w += v.w * m;
        }
        if (q > 0) qbuf[q - 1][c4] = acc;
        __syncthreads();
        if (q == 0) {
            const float4 a1 = qbuf[0][c4], a2 = qbuf[1][c4], a3 = qbuf[2][c4];
            const float inv = 1.0f / fmaxf(cntsh, 1e-9f);
            float4 r;
            r.x = (acc.x + a1.x + a2.x + a3.x) * inv;
            r.y = (acc.y + a1.y + a2.y + a3.y) * inv;
            r.z = (acc.z + a1.z + a2.z + a3.z) * inv;
            r.w = (acc.w + a1.w + a2.w + a3.w) * inv;
            ((float4*)prelogits)[(size_t)b * H4 + c4] = r;
        }
    }
    __threadfence();
    grid.sync();

    // ================= phase 2a: xS GEMM tile (rt, cs) =================
    {
        const int rt = bid >> 3, cs = bid & 7;
        const int r0 = rt * 8, cb = cs * 24;
        const int kg = t / 24, c4 = t % 24;      // kg 0..31 (24-k slice each)

        for (int i = t; i < 8 * H4; i += 768)
            ((float4*)xsl)[i] = ((const float4*)prelogits)[(size_t)(r0 + i / H4) * H4 + (i % H4)];
        __syncthreads();

        float4 acc[8];
#pragma unroll
        for (int r = 0; r < 8; ++r) acc[r] = make_float4(0.f, 0.f, 0.f, 0.f);
        const float4* cov4 = (const float4*)cov + cb + c4;
#pragma unroll 4
        for (int kk = 0; kk < 24; ++kk) {
            const int k = kg * 24 + kk;
            const float4 cv = cov4[(size_t)k * H4];
#pragma unroll
            for (int r = 0; r < 8; ++r) {
                const float xv = xsl[r * H + k];
                acc[r].x += xv * cv.x; acc[r].y += xv * cv.y;
                acc[r].z += xv * cv.z; acc[r].w += xv * cv.w;
            }
        }

        float pdr[8];
#pragma unroll
        for (int r = 0; r < 8; ++r) pdr[r] = 0.f;
        for (int r = 0; r < 8; ++r) {
            red2[kg][c4] = acc[r];
            __syncthreads();
            if (kg == 0) {
                float4 s = red2[0][c4];
#pragma unroll
                for (int g = 1; g < 32; ++g) {
                    const float4 q2 = red2[g][c4];
                    s.x += q2.x; s.y += q2.y; s.z += q2.z; s.w += q2.w;
                }
                xsf[r][c4] = s;
                const float4 xv = ((float4*)xsl)[r * H4 + cb + c4];
                pdr[r] = s.x * xv.x + s.y * xv.y + s.z * xv.z + s.w * xv.w;
            }
            __syncthreads();
        }

        if (t < 64) {
#pragma unroll
            for (int r = 0; r < 8; ++r) {
                float v = (t < 24) ? pdr[r] : 0.f;
#pragma unroll
                for (int off = 16; off > 0; off >>= 1) v += __shfl_down(v, off, 32);
                if (t == 0) tx_part[cs * 256 + r0 + r] = v;
            }
        }

        if (t < C) {
            const float4* mu4 = (const float4*)means + (size_t)t * H4 + cb;
            float a8[8];
#pragma unroll
            for (int r = 0; r < 8; ++r) a8[r] = 0.f;
#pragma unroll 4
            for (int j = 0; j < 24; ++j) {
                const float4 mv = mu4[j];
#pragma unroll
                for (int r = 0; r < 8; ++r) {
                    const float4 x = xsf[r][j];
                    a8[r] += mv.x * x.x + mv.y * x.y + mv.z * x.z + mv.w * x.w;
                }
            }
#pragma unroll
            for (int r = 0; r < 8; ++r)
                dp[((size_t)(cs * 256) + (r0 + r)) * 150 + t] = a8[r];
        }
    }

    // ================= phase 2b: tm job (blocks 0..151) =================
    if (bid < 152) {
        __syncthreads();                      // protect xsl reuse
        const int rt = bid >> 3, cs = bid & 7;
        const int r0 = rt * 8, cb = cs * 24;
        const int kg = t / 24, c4 = t % 24;

        for (int i = t; i < 8 * H4; i += 768) {
            const int row = r0 + i / H4;
            float4 v = make_float4(0.f, 0.f, 0.f, 0.f);
            if (row < C) v = ((const float4*)means)[(size_t)row * H4 + (i % H4)];
            ((float4*)xsl)[i] = v;
        }
        __syncthreads();

        float4 acc[8];
#pragma unroll
        for (int r = 0; r < 8; ++r) acc[r] = make_float4(0.f, 0.f, 0.f, 0.f);
        const float4* cov4 = (const float4*)cov + cb + c4;
#pragma unroll 4
        for (int kk = 0; kk < 24; ++kk) {
            const int k = kg * 24 + kk;
            const float4 cv = cov4[(size_t)k * H4];
#pragma unroll
            for (int r = 0; r < 8; ++r) {
                const float xv = xsl[r * H + k];
                acc[r].x += xv * cv.x; acc[r].y += xv * cv.y;
                acc[r].z += xv * cv.z; acc[r].w += xv * cv.w;
            }
        }
        const int w = t >> 6;
#pragma unroll
        for (int r = 0; r < 8; ++r) {
            const float4 mu = ((float4*)xsl)[r * H4 + cb + c4];
            float pd = acc[r].x * mu.x + acc[r].y * mu.y + acc[r].z * mu.z + acc[r].w * mu.w;
#pragma unroll
            for (int off = 32; off > 0; off >>= 1) pd += __shfl_down(pd, off, 64);
            if ((t & 63) == 0) sred[r][w] = pd;
        }
        __syncthreads();
        if (t < 8) {
            const int row = r0 + t;
            if (row < C) {
                float s = 0.f;
#pragma unroll
                for (int j = 0; j < 12; ++j) s += sred[t][j];
                tm_part[cs * 152 + row] = s;
            }
        }
    }
    __threadfence();
    grid.sync();

    // ================= phase 3: scores + argmin (b = bid) =================
    {
        const int b = bid;
        if (t < 192) {
            float sc = INFINITY;
            if (t < C) {
                float d = 0.f;
#pragma unroll
                for (int j = 0; j < 8; ++j) d += dp[((size_t)(j * 256) + b) * 150 + t];
                float tx = 0.f;
#pragma unroll
                for (int j = 0; j < 8; ++j) tx += tx_part[j * 256 + b];
                float tm = 0.f;
#pragma unroll
                for (int j = 0; j < 8; ++j) tm += tm_part[j * 152 + t];
                sc = tx - 2.0f * d + tm;
                out[B + (size_t)t * B + b] = sc;
            }
            sv[t] = sc;
            si[t] = (t < C) ? t : 0x7fffffff;
        }
        __syncthreads();
#pragma unroll
        for (int off = 96; off >= 3; off >>= 1) {
            if (t < off) {
                const float ov = sv[t + off];
                const int oi = si[t + off];
                if (ov < sv[t] || (ov == sv[t] && oi < si[t])) { sv[t] = ov; si[t] = oi; }
            }
            __syncthreads();
        }
        if (t == 0) {
            float bv = sv[0];
            int bi = si[0];
#pragma unroll
            for (int j = 1; j < 3; ++j)
                if (sv[j] < bv || (sv[j] == bv && si[j] < bi)) { bv = sv[j]; bi = si[j]; }
            out[b] = (float)bi;
        }
    }
}

extern "C" void kernel_launch(void* const* d_in, const int* in_sizes, int n_in,
                              void* d_out, int out_size, void* d_ws, size_t ws_size,
                              hipStream_t stream) {
    const float* lhs   = (const float*)d_in[0];   // [B,S,H] f32
    const int*   mask  = (const int*)d_in[1];     // [B,S] i32
    const float* means = (const float*)d_in[2];   // [C,H] f32
    const float* cov   = (const float*)d_in[3];   // [H,H] f32
    float* out = (float*)d_out;
    char* ws = (char*)d_ws;

    float* prelogits = (float*)(ws + 0);
    float* dp        = (float*)(ws + 786432);
    float* tx_part   = (float*)(ws + 2015232);
    float* tm_part   = (float*)(ws + 2023424);

    void* args[] = {(void*)&lhs, (void*)&mask, (void*)&means, (void*)&cov,
                    (void*)&prelogits, (void*)&dp, (void*)&tx_part,
                    (void*)&tm_part, (void*)&out};
    hipLaunchCooperativeKernel((void*)kMega, dim3(B), dim3(768), args, 0, stream);
}

// Round 14
// 56.067 us; speedup vs baseline: 3.8564x; 3.8564x over previous
//
#include <hip/hip_runtime.h>
#include <hip/hip_bf16.h>

// Problem constants
#define B 256
#define S 256
#define H 768
#define C 150
#define H4 192              // H / 4 (float4 columns)

// ws layout (bytes):
//  prelogits : 0        .. 786432    [256][768] f32 (finalized pooled rows)
//  dp        : 786432   .. 2015232   [8][256][150] f32 score-dot partials
//  tx_part   : 2015232  .. 2023424   [8][256] f32
//  tm_part   : 2023424  .. 2028288   [8][152] f32

// ---------------------------------------------------------------------------
// kPool: one block per batch row b. 768 threads = 4 lanes-of-rows x 192
// f4-cols; quarter q owns rows {4s+q}, so each iteration the block reads ONE
// contiguous 12 KB chunk (rows 4s..4s+3) -> single linear stream per block.
// Quarters combined via LDS, finalized in-kernel. Grid 256 = 1 block/CU.
// ---------------------------------------------------------------------------
__global__ __launch_bounds__(768) void kPool(const float* __restrict__ lhs,
                                             const int* __restrict__ mask,
                                             float* __restrict__ prelogits) {
    const int b = blockIdx.x;
    const int t = threadIdx.x;
    const int q = t / H4, c4 = t - q * H4;   // quarter 0..3, f4-col 0..191
    __shared__ float msk[S];                 // 1 KB
    __shared__ float4 qbuf[3][H4];           // 9 KB
    __shared__ float cntsh;

    if (t < S) msk[t] = (float)mask[b * S + t];
    __syncthreads();

    // last wave computes the mask count before starting its stream
    if (t >= 704) {
        const int idx = t - 704;             // 0..63
        float v = msk[idx] + msk[idx + 64] + msk[idx + 128] + msk[idx + 192];
#pragma unroll
        for (int off = 32; off > 0; off >>= 1) v += __shfl_down(v, off, 64);
        if (idx == 0) cntsh = v;
    }

    // quarter q starts at row q; advances 4 rows per iteration (linear stream)
    const float4* src = (const float4*)lhs + ((size_t)b * S + q) * H4 + c4;
    float4 acc = make_float4(0.f, 0.f, 0.f, 0.f);
#pragma unroll 8
    for (int s = 0; s < 64; ++s) {
        const float m = msk[s * 4 + q];
        const float4 v = src[(size_t)s * 4 * H4];
        acc.x += v.x * m; acc.y += v.y * m; acc.z += v.z * m; acc.w += v.w * m;
    }
    if (q > 0) qbuf[q - 1][c4] = acc;
    __syncthreads();
    if (q == 0) {
        const float4 a1 = qbuf[0][c4], a2 = qbuf[1][c4], a3 = qbuf[2][c4];
        const float inv = 1.0f / fmaxf(cntsh, 1e-9f);
        float4 r;
        r.x = (acc.x + a1.x + a2.x + a3.x) * inv;
        r.y = (acc.y + a1.y + a2.y + a3.y) * inv;
        r.z = (acc.z + a1.z + a2.z + a3.z) * inv;
        r.w = (acc.w + a1.w + a2.w + a3.w) * inv;
        ((float4*)prelogits)[(size_t)b * H4 + c4] = r;
    }
}

// ---------------------------------------------------------------------------
// kC: blocks 0..255  : xS col-slice GEMM (prelogits read straight into LDS)
//                      + t_x partials + score-dot partials vs all 150 means.
//     blocks 256..407: t_m partials (means @ cov . means), no pool dependency.
// block 192 = 8 kg x 24 f4-cols.
// ---------------------------------------------------------------------------
__global__ __launch_bounds__(192) void kC(const float* __restrict__ prelogits,
                                          const float* __restrict__ cov,
                                          const float* __restrict__ means,
                                          float* __restrict__ dp,
                                          float* __restrict__ tx_part,
                                          float* __restrict__ tm_part) {
    const int t = threadIdx.x;
    const int kg = t / 24, c4 = t % 24;
    __shared__ float xsl[8 * H];          // 24 KB
    __shared__ float4 red2[8][24];        // 3 KB
    __shared__ float4 xsf[8][24];         // 3 KB
    __shared__ float sred[8][3];

    if (blockIdx.x < 256) {
        const int rt = blockIdx.x >> 3, cs = blockIdx.x & 7;
        const int r0 = rt * 8, cb = cs * 24;

        // load pooled rows into LDS (already finalized)
#pragma unroll
        for (int r = 0; r < 8; ++r)
            ((float4*)xsl)[r * H4 + t] = ((const float4*)prelogits)[(size_t)(r0 + r) * H4 + t];
        __syncthreads();

        float4 acc[8];
#pragma unroll
        for (int r = 0; r < 8; ++r) acc[r] = make_float4(0.f, 0.f, 0.f, 0.f);
        const float4* cov4 = (const float4*)cov + cb + c4;
#pragma unroll 4
        for (int kk = 0; kk < 96; ++kk) {
            const int k = kg * 96 + kk;
            const float4 cv = cov4[(size_t)k * H4];
#pragma unroll
            for (int r = 0; r < 8; ++r) {
                const float xv = xsl[r * H + k];
                acc[r].x += xv * cv.x; acc[r].y += xv * cv.y;
                acc[r].z += xv * cv.z; acc[r].w += xv * cv.w;
            }
        }

        float pdr[8];
#pragma unroll
        for (int r = 0; r < 8; ++r) pdr[r] = 0.f;
        for (int r = 0; r < 8; ++r) {
            red2[kg][c4] = acc[r];
            __syncthreads();
            if (kg == 0) {
                float4 s = red2[0][c4];
#pragma unroll
                for (int g = 1; g < 8; ++g) {
                    const float4 q = red2[g][c4];
                    s.x += q.x; s.y += q.y; s.z += q.z; s.w += q.w;
                }
                xsf[r][c4] = s;
                const float4 xv = ((float4*)xsl)[r * H4 + cb + c4];
                pdr[r] = s.x * xv.x + s.y * xv.y + s.z * xv.z + s.w * xv.w;
            }
            __syncthreads();
        }

        // t_x partials (lanes 0..23 hold contributions)
        if (t < 64) {
#pragma unroll
            for (int r = 0; r < 8; ++r) {
                float v = (t < 24) ? pdr[r] : 0.f;
#pragma unroll
                for (int off = 16; off > 0; off >>= 1) v += __shfl_down(v, off, 32);
                if (t == 0) tx_part[cs * 256 + r0 + r] = v;
            }
        }

        // score-dot partials: thread t = class c, stream means slice from L2
        if (t < C) {
            const float4* mu4 = (const float4*)means + (size_t)t * H4 + cb;
            float a8[8];
#pragma unroll
            for (int r = 0; r < 8; ++r) a8[r] = 0.f;
#pragma unroll 4
            for (int j = 0; j < 24; ++j) {
                const float4 mv = mu4[j];
#pragma unroll
                for (int r = 0; r < 8; ++r) {
                    const float4 x = xsf[r][j];
                    a8[r] += mv.x * x.x + mv.y * x.y + mv.z * x.z + mv.w * x.w;
                }
            }
#pragma unroll
            for (int r = 0; r < 8; ++r)
                dp[((size_t)(cs * 256) + (r0 + r)) * 150 + t] = a8[r];
        }
    } else {
        // ---- t_m partials: rows r0..r0+7 of means, f4-cols cb..cb+23, k-split 8 ----
        const int idx = blockIdx.x - 256;
        const int rt = idx >> 3, cs = idx & 7;
        const int r0 = rt * 8, cb = cs * 24;

        for (int r = 0; r < 8; ++r) {
            const int row = r0 + r;
            float4 v = make_float4(0.f, 0.f, 0.f, 0.f);
            if (row < C) v = ((const float4*)means)[(size_t)row * H4 + t];
            ((float4*)xsl)[r * H4 + t] = v;
        }
        __syncthreads();

        float4 acc[8];
#pragma unroll
        for (int r = 0; r < 8; ++r) acc[r] = make_float4(0.f, 0.f, 0.f, 0.f);
        const float4* cov4 = (const float4*)cov + cb + c4;
#pragma unroll 4
        for (int kk = 0; kk < 96; ++kk) {
            const int k = kg * 96 + kk;
            const float4 cv = cov4[(size_t)k * H4];
#pragma unroll
            for (int r = 0; r < 8; ++r) {
                const float xv = xsl[r * H + k];
                acc[r].x += xv * cv.x; acc[r].y += xv * cv.y;
                acc[r].z += xv * cv.z; acc[r].w += xv * cv.w;
            }
        }
        const int w = t >> 6;
#pragma unroll
        for (int r = 0; r < 8; ++r) {
            const float4 mu = ((float4*)xsl)[r * H4 + cb + c4];
            float pd = acc[r].x * mu.x + acc[r].y * mu.y + acc[r].z * mu.z + acc[r].w * mu.w;
#pragma unroll
            for (int off = 32; off > 0; off >>= 1) pd += __shfl_down(pd, off, 64);
            if ((t & 63) == 0) sred[r][w] = pd;
        }
        __syncthreads();
        if (t < 8) {
            const int row = r0 + t;
            if (row < C)
                tm_part[cs * 152 + row] = sred[t][0] + sred[t][1] + sred[t][2];
        }
    }
}

// ---------------------------------------------------------------------------
// kD: reduce partials -> scores + argmin. One block per b, 192 threads.
// ---------------------------------------------------------------------------
__global__ __launch_bounds__(192) void kD(const float* __restrict__ dp,
                                          const float* __restrict__ tx_part,
                                          const float* __restrict__ tm_part,
                                          float* __restrict__ out) {
    const int b = blockIdx.x, t = threadIdx.x;
    __shared__ float sv[192];
    __shared__ int si[192];

    float sc = INFINITY;
    if (t < C) {
        float d = 0.f;
#pragma unroll
        for (int j = 0; j < 8; ++j) d += dp[((size_t)(j * 256) + b) * 150 + t];
        float tx = 0.f;
#pragma unroll
        for (int j = 0; j < 8; ++j) tx += tx_part[j * 256 + b];
        float tm = 0.f;
#pragma unroll
        for (int j = 0; j < 8; ++j) tm += tm_part[j * 152 + t];
        sc = tx - 2.0f * d + tm;
        out[B + (size_t)t * B + b] = sc;
    }
    sv[t] = sc;
    si[t] = (t < C) ? t : 0x7fffffff;
    __syncthreads();
#pragma unroll
    for (int off = 96; off >= 3; off >>= 1) {
        if (t < off) {
            const float ov = sv[t + off];
            const int oi = si[t + off];
            if (ov < sv[t] || (ov == sv[t] && oi < si[t])) { sv[t] = ov; si[t] = oi; }
        }
        __syncthreads();
    }
    if (t == 0) {
        float bv = sv[0];
        int bi = si[0];
#pragma unroll
        for (int j = 1; j < 3; ++j)
            if (sv[j] < bv || (sv[j] == bv && si[j] < bi)) { bv = sv[j]; bi = si[j]; }
        out[b] = (float)bi;
    }
}

extern "C" void kernel_launch(void* const* d_in, const int* in_sizes, int n_in,
                              void* d_out, int out_size, void* d_ws, size_t ws_size,
                              hipStream_t stream) {
    const float* lhs   = (const float*)d_in[0];   // [B,S,H] f32
    const int*   mask  = (const int*)d_in[1];     // [B,S] i32
    const float* means = (const float*)d_in[2];   // [C,H] f32
    const float* cov   = (const float*)d_in[3];   // [H,H] f32
    float* out = (float*)d_out;
    char* ws = (char*)d_ws;

    float* prelogits = (float*)(ws + 0);
    float* dp        = (float*)(ws + 786432);
    float* tx_part   = (float*)(ws + 2015232);
    float* tm_part   = (float*)(ws + 2023424);

    kPool<<<dim3(B), 768, 0, stream>>>(lhs, mask, prelogits);
    kC<<<dim3(256 + 152), 192, 0, stream>>>(prelogits, cov, means, dp, tx_part, tm_part);
    kD<<<dim3(256), 192, 0, stream>>>(dp, tx_part, tm_part, out);
}